// Round 11
// baseline (166.515 us; speedup 1.0000x reference)
//
#include <hip/hip_runtime.h>
#include <math.h>

#define B_ 4
#define L_ 4096
#define D_ 256
#define A_ 64
#define M_ (B_*L_)   // 16384 flat rows

typedef _Float16 half4 __attribute__((ext_vector_type(4)));
typedef _Float16 half8 __attribute__((ext_vector_type(8)));
typedef __attribute__((ext_vector_type(4))) float floatx4;

__device__ __forceinline__ unsigned short f2h_(float f) {
    _Float16 h = (_Float16)f;
    return __builtin_bit_cast(unsigned short, h);
}
__device__ __forceinline__ float h2f_(unsigned short u) {
    return (float)__builtin_bit_cast(_Float16, u);
}

// fp16 partial-slot element offsets (slot s holds rows l>=512s, packed):
// poff[s] = sum_{s'=1..s-1} 4*(4096-512*s')*64
__device__ __constant__ int c_poff[8] =
    {0, 0, 917504, 1703936, 2359296, 2883584, 3276800, 3538944};

// ---------------------------------------------------------------------------
// wconv: W f32 [256][64] -> W^T fp16 [64][256]. Wq scaled by 1/ln2 (exp2
// softmax domain). grid (3), block 256.
// ---------------------------------------------------------------------------
__global__ __launch_bounds__(256) void wconv_kernel(
    const float* __restrict__ Wq, const float* __restrict__ Wk,
    const float* __restrict__ Wv, unsigned short* __restrict__ wt)
{
    const int w = blockIdx.x, t = threadIdx.x;
    const float* W = (w == 0) ? Wq : (w == 1) ? Wk : Wv;
    unsigned short* o = wt + w * A_ * D_;
    const float scale = (w == 0) ? 1.44269504f : 1.0f;
    __shared__ float T[A_ * 260];
    #pragma unroll
    for (int p = 0; p < 16; ++p) {
        int idx = p * 256 + t;
        int d = idx >> 4, a4 = (idx & 15) * 4;
        float4 v = *(const float4*)(W + d * A_ + a4);
        T[(a4 + 0) * 260 + d] = v.x * scale;
        T[(a4 + 1) * 260 + d] = v.y * scale;
        T[(a4 + 2) * 260 + d] = v.z * scale;
        T[(a4 + 3) * 260 + d] = v.w * scale;
    }
    __syncthreads();
    const int a = t >> 2, d0 = (t & 3) * 64;
    #pragma unroll
    for (int i = 0; i < 16; ++i) {
        float4 v = *(const float4*)(&T[a * 260 + d0 + 4 * i]);
        ushort4 s;
        s.x = f2h_(v.x); s.y = f2h_(v.y); s.z = f2h_(v.z); s.w = f2h_(v.w);
        *(ushort4*)(o + a * D_ + d0 + 4 * i) = s;
    }
}

// ---------------------------------------------------------------------------
// proj (R5 known-good): one block per 32 x-rows computes ALL 3 projections.
// grid (M/32), block 384 = 6 waves (w = wid>>1, mt = wid&1).
// q/k fp16 [M][64]; v fp16 TRANSPOSED [B][64][L] (64B-aligned line stores).
// ---------------------------------------------------------------------------
__global__ __launch_bounds__(384) void proj_kernel(
    const float* __restrict__ x,           // [M][256] f32
    const unsigned short* __restrict__ wt, // [3][64][256] fp16 (W^T)
    unsigned short* __restrict__ qo,
    unsigned short* __restrict__ ko,
    unsigned short* __restrict__ vto)
{
    __shared__ __align__(16) unsigned short Xh[32 * 264];   // 16.5 KB
    __shared__ __align__(16) unsigned short Cst[6 * 1536];  // 18 KB
    const int t = threadIdx.x, m0 = blockIdx.x * 32;

    #pragma unroll
    for (int p = 0; p < 6; ++p) {
        int idx = p * 384 + t;
        if (idx < 2048) {
            int row = idx >> 6, col = (idx & 63) * 4;
            float4 v = *(const float4*)(x + (size_t)(m0 + row) * D_ + col);
            ushort4 s;
            s.x = f2h_(v.x); s.y = f2h_(v.y); s.z = f2h_(v.z); s.w = f2h_(v.w);
            *(ushort4*)(Xh + row * 264 + col) = s;
        }
    }
    __syncthreads();

    const int wid = t >> 6, lane = t & 63, c = lane & 15, g = lane >> 4;
    const int w = wid >> 1, mt = wid & 1;

    half8 xa[8];
    #pragma unroll
    for (int s = 0; s < 8; ++s)
        xa[s] = *(const half8*)(Xh + (16 * mt + c) * 264 + 32 * s + 8 * g);

    const unsigned short* wsrc = wt + w * A_ * D_;
    unsigned short* Cw = Cst + wid * 1536;
    #pragma unroll
    for (int nt = 0; nt < 4; ++nt) {
        floatx4 acc = {0.f, 0.f, 0.f, 0.f};
        #pragma unroll
        for (int s = 0; s < 8; ++s) {
            half8 wb = *(const half8*)(wsrc + (16 * nt + c) * D_ + 32 * s + 8 * g);
            acc = __builtin_amdgcn_mfma_f32_16x16x32_f16(xa[s], wb, acc, 0, 0, 0);
        }
        if (w < 2) {
            #pragma unroll
            for (int r = 0; r < 4; ++r)
                Cw[(4 * g + r) * 72 + 16 * nt + c] = f2h_(acc[r]);      // [m16][72]
        } else {
            #pragma unroll
            for (int r = 0; r < 4; ++r)
                Cw[(16 * nt + c) * 24 + 4 * g + r] = f2h_(acc[r]);      // [a64][24]
        }
    }

    if (w < 2) {
        unsigned short* o = (w == 0) ? qo : ko;
        const int row16 = lane >> 2, seg = lane & 3;
        uint4 d0 = *(const uint4*)(Cw + row16 * 72 + seg * 16);
        uint4 d1 = *(const uint4*)(Cw + row16 * 72 + seg * 16 + 8);
        unsigned short* p = o + (size_t)(m0 + 16 * mt + row16) * A_ + seg * 16;
        *(uint4*)(p) = d0;
        *(uint4*)(p + 8) = d1;
    }
    __syncthreads();
    if (t < 256) {
        const int a = t >> 2, quarter = t & 3;
        const int o = quarter * 8, mtv = o >> 4, idx = o & 15;
        uint4 d = *(const uint4*)(Cst + (4 + mtv) * 1536 + a * 24 + idx);
        const int bb = m0 >> 12, l0 = m0 & (L_ - 1);
        *(uint4*)(vto + ((size_t)(bb * A_ + a)) * L_ + l0 + o) = d;
    }
}

// ---------------------------------------------------------------------------
// attn: BALANCED split-K flash (R5 loop verbatim, chunked tile ranges).
// grid (32, 128): x = s + 8*b (s = chunk 0..7, b = batch), y -> qt = 127-y
// (heavy q-tiles of ALL batches dispatch first). T = (qt>>1)+1 tiles;
// ns = ceil(T/8); block (qt,s) handles tiles [8s, min(T,8s+8)) -> every
// active block has a <=4-round chain (R5's worst was 16). s >= ns exits.
// 4 waves = 2 qsub x 2 phase; K/V LDS-staged 2 tiles/round (pad 72).
// Partial (unnormalized O + (m,l)): s=0 -> out (f32) + mls[0];
// s>=1 -> packed fp16 buffer (slot s holds only rows l>=512s) + mls[s].
// ---------------------------------------------------------------------------
__global__ __launch_bounds__(256) void attn_kernel(
    const unsigned short* __restrict__ qb,  // [B][L][64] fp16 (x 1/ln2)
    const unsigned short* __restrict__ kb,  // [B][L][64] fp16
    const unsigned short* __restrict__ vt,  // [B][64][L] fp16
    float* __restrict__ out,                // partial O for s=0
    unsigned short* __restrict__ pack,      // fp16 partials s=1..7 (packed)
    float2* __restrict__ mls)               // (m,l) [8][M]
{
    __shared__ __align__(16) unsigned short smem[4 * 4608];  // 36 KB
    unsigned short* Ks = smem;
    unsigned short* Vs = smem + 2 * 4608;

    const int t    = threadIdx.x;
    const int lane = t & 63;
    const int wid  = t >> 6;
    const int qsub = wid >> 1;
    const int ph   = wid & 1;
    const int c    = lane & 15;
    const int g    = lane >> 4;
    const int s    = blockIdx.x & 7;
    const int b    = blockIdx.x >> 3;
    const int qt   = 127 - blockIdx.y;    // heavy q-tiles first
    const int q0   = qt * 32;

    const int T  = (qt >> 1) + 1;
    const int ns = (T + 7) >> 3;
    if (s >= ns) return;                  // uniform early-exit

    const int qrow0 = q0 + 16 * qsub;
    const int qme   = qrow0 + c;

    const size_t base  = (size_t)b * L_ * A_;
    const size_t vbase = (size_t)b * A_ * L_;

    half8 qf[2];
    {
        const unsigned short* qp = qb + base + (size_t)(qrow0 + c) * A_ + g * 8;
        qf[0] = *(const half8*)(qp);
        qf[1] = *(const half8*)(qp + 32);
    }

    floatx4 O4[4];          // O^T[a=16at+4g+r][q=c], unnormalized
    #pragma unroll
    for (int at = 0; at < 4; ++at) O4[at] = (floatx4){0.f, 0.f, 0.f, 0.f};
    float m_ = -INFINITY, l_ = 0.f;

    const int t0  = 8 * s;
    const int t1  = min(T, t0 + 8);
    const int nIt = (t1 - t0 + 1) >> 1;
    const int Tm1 = T - 1;

    for (int it = 0; it < nIt; ++it) {
        __syncthreads();
        #pragma unroll
        for (int tile = 0; tile < 2; ++tile) {
            const int kts = t0 + 2 * it + tile;
            if (kts < t1) {
                const int k0s = kts << 6;
                #pragma unroll
                for (int i = 0; i < 2; ++i) {
                    const int cid = t + (i << 8);
                    const int row = cid >> 3, c8 = cid & 7;
                    uint4 dK = *(const uint4*)(kb + base + (size_t)k0s * 64 + cid * 8);
                    *(uint4*)(Ks + tile * 4608 + row * 72 + c8 * 8) = dK;
                    uint4 dV = *(const uint4*)(vt + vbase + (size_t)row * L_ + k0s + c8 * 8);
                    *(uint4*)(Vs + tile * 4608 + row * 72 + c8 * 8) = dV;
                }
            }
        }
        __syncthreads();

        const int kt = t0 + 2 * it + ph;
        if (kt >= t1) continue;          // loop-top barriers stay convergent
        const int k0 = kt << 6;
        const unsigned short* Kw = Ks + ph * 4608;
        const unsigned short* Vw = Vs + ph * 4608;

        // ---- S^T = K . Q^T ----
        floatx4 S4[4];
        #pragma unroll
        for (int nt = 0; nt < 4; ++nt) S4[nt] = (floatx4){0.f, 0.f, 0.f, 0.f};
        #pragma unroll
        for (int ss = 0; ss < 2; ++ss)
            #pragma unroll
            for (int nt = 0; nt < 4; ++nt) {
                half8 kf = *(const half8*)(Kw + (16 * nt + c) * 72 + 32 * ss + 8 * g);
                S4[nt] = __builtin_amdgcn_mfma_f32_16x16x32_f16(kf, qf[ss], S4[nt], 0, 0, 0);
            }

        // ---- causal mask: only global tile T-1 straddles the diagonal ----
        if (kt == Tm1) {
            #pragma unroll
            for (int nt = 0; nt < 4; ++nt)
                #pragma unroll
                for (int r = 0; r < 4; ++r)
                    if (k0 + 16 * nt + 4 * g + r > qme) S4[nt][r] = -INFINITY;
        }

        // ---- online softmax (exp2 domain; per-lane q row) ----
        float tm = fmaxf(fmaxf(fmaxf(S4[0][0], S4[0][1]), fmaxf(S4[0][2], S4[0][3])),
                         fmaxf(fmaxf(S4[1][0], S4[1][1]), fmaxf(S4[1][2], S4[1][3])));
        tm = fmaxf(tm, fmaxf(fmaxf(fmaxf(S4[2][0], S4[2][1]), fmaxf(S4[2][2], S4[2][3])),
                             fmaxf(fmaxf(S4[3][0], S4[3][1]), fmaxf(S4[3][2], S4[3][3]))));
        tm = fmaxf(tm, __shfl_xor(tm, 16));
        tm = fmaxf(tm, __shfl_xor(tm, 32));
        const float mn  = fmaxf(m_, tm);
        const float mnc = fmaxf(mn, -3.0e38f);         // guard -inf - -inf
        const float al  = exp2f(fminf(m_ - mnc, 0.f)); // m_=-inf -> 0
        float rs = 0.f;
        half4 pfr[4];
        #pragma unroll
        for (int nt = 0; nt < 4; ++nt) {
            #pragma unroll
            for (int r = 0; r < 4; ++r) {
                float pv = exp2f(S4[nt][r] - mnc);      // masked: exp2(-inf)=0
                S4[nt][r] = pv;
                rs += pv;
            }
            pfr[nt][0] = (_Float16)S4[nt][0];
            pfr[nt][1] = (_Float16)S4[nt][1];
            pfr[nt][2] = (_Float16)S4[nt][2];
            pfr[nt][3] = (_Float16)S4[nt][3];
        }
        rs += __shfl_xor(rs, 16);
        rs += __shfl_xor(rs, 32);
        l_ = l_ * al + rs;
        m_ = mn;

        // ---- O^T = O^T*al + V^T . P^T ----
        #pragma unroll
        for (int at = 0; at < 4; ++at) {
            O4[at] *= al;
            #pragma unroll
            for (int nt = 0; nt < 4; ++nt) {
                half4 va = *(const half4*)(Vw + (16 * at + c) * 72 + 16 * nt + 4 * g);
                O4[at] = __builtin_amdgcn_mfma_f32_16x16x16f16(va, pfr[nt], O4[at], 0, 0, 0);
            }
        }
    }

    // ---- combine 2 phases per qsub; write unnormalized partial ----
    __syncthreads();
    float*  Of  = (float*)smem;                 // [wid][at][lane][r] 16 KB
    float2* mlq = (float2*)(smem + 8192);       // byte offset 16384
    #pragma unroll
    for (int at = 0; at < 4; ++at) {
        float4 v; v.x = O4[at][0]; v.y = O4[at][1]; v.z = O4[at][2]; v.w = O4[at][3];
        ((float4*)Of)[wid * 256 + at * 64 + lane] = v;
    }
    if (g == 0) { float2 ml; ml.x = m_; ml.y = l_; mlq[wid * 16 + c] = ml; }
    __syncthreads();

    {
        const int q32 = t >> 3, seg = t & 7;
        const int qs = q32 >> 4, cc = q32 & 15;
        const float2 A0 = mlq[(2 * qs) * 16 + cc];
        const float2 A1 = mlq[(2 * qs + 1) * 16 + cc];
        const float mf = fmaxf(A0.x, A1.x);
        const float mc = fmaxf(mf, -3.0e38f);
        const float w0 = exp2f(A0.x - mc);      // -inf -> 0
        const float w1 = exp2f(A1.x - mc);
        const float ls = w0 * A0.y + w1 * A1.y;
        float res[8];
        #pragma unroll
        for (int u = 0; u < 8; ++u) {
            const int a = seg * 8 + u;
            const int at = a >> 4, gg = (a >> 2) & 3, r = a & 3;
            const int i0 = ((2 * qs) * 256 + at * 64 + gg * 16 + cc) * 4 + r;
            const int i1 = ((2 * qs + 1) * 256 + at * 64 + gg * 16 + cc) * 4 + r;
            res[u] = w0 * Of[i0] + w1 * Of[i1];
        }
        const int l = q0 + q32;
        if (s == 0) {
            float* p = out + base + (size_t)l * A_ + seg * 8;
            *(float4*)(p)     = make_float4(res[0], res[1], res[2], res[3]);
            *(float4*)(p + 4) = make_float4(res[4], res[5], res[6], res[7]);
        } else {
            const int rows_s = 4096 - 512 * s;
            unsigned short* p = pack + c_poff[s]
                + (((size_t)(b * rows_s + (l - 512 * s))) << 6) + seg * 8;
            ushort4 u0, u1;
            u0.x = f2h_(res[0]); u0.y = f2h_(res[1]); u0.z = f2h_(res[2]); u0.w = f2h_(res[3]);
            u1.x = f2h_(res[4]); u1.y = f2h_(res[5]); u1.z = f2h_(res[6]); u1.w = f2h_(res[7]);
            *(ushort4*)(p)     = u0;
            *(ushort4*)(p + 4) = u1;
        }
        if (seg == 0) {
            float2 ml; ml.x = mf; ml.y = ls;
            mls[(size_t)s * M_ + b * L_ + l] = ml;
        }
    }
}

// ---------------------------------------------------------------------------
// merge: final = sum_s(O_s * w_s) / sum_s(l_s * w_s), variable ns per row.
// grid (256), block 256: thread handles one q-row 16-float segment.
// ---------------------------------------------------------------------------
__global__ __launch_bounds__(256) void merge_kernel(
    float* __restrict__ out, const unsigned short* __restrict__ pack,
    const float2* __restrict__ mls)
{
    const int tid = blockIdx.x * 256 + threadIdx.x;   // 65536
    const int q = tid >> 2, seg = tid & 3;            // q in [0,M)
    const int l = q & (L_ - 1), b = q >> 12;
    const int qt = l >> 5;
    const int T  = (qt >> 1) + 1;
    const int ns = (T + 7) >> 3;

    float2 a[8];
    a[0] = mls[q];
    float mf = a[0].x;
    for (int s = 1; s < ns; ++s) { a[s] = mls[(size_t)s * M_ + q]; mf = fmaxf(mf, a[s].x); }
    float w[8], lsum = 0.f;
    for (int s = 0; s < ns; ++s) { w[s] = exp2f(a[s].x - mf); lsum += w[s] * a[s].y; }
    const float inv = 1.f / lsum;

    float acc[16];
    {
        const float* p = out + (size_t)q * A_ + seg * 16;
        #pragma unroll
        for (int u = 0; u < 16; ++u) acc[u] = w[0] * p[u];
    }
    for (int s = 1; s < ns; ++s) {
        const int rows_s = 4096 - 512 * s;
        const unsigned short* p = pack + c_poff[s]
            + (((size_t)(b * rows_s + (l - 512 * s))) << 6) + seg * 16;
        #pragma unroll
        for (int u = 0; u < 16; ++u) acc[u] += w[s] * h2f_(p[u]);
    }
    float* o = out + (size_t)q * A_ + seg * 16;
    #pragma unroll
    for (int u = 0; u < 4; ++u)
        *(float4*)(o + 4 * u) = make_float4(acc[4*u] * inv, acc[4*u+1] * inv,
                                            acc[4*u+2] * inv, acc[4*u+3] * inv);
}

// ---------------------------------------------------------------------------
extern "C" void kernel_launch(void* const* d_in, const int* in_sizes, int n_in,
                              void* d_out, int out_size, void* d_ws, size_t ws_size,
                              hipStream_t stream) {
    const float* x  = (const float*)d_in[0];
    const float* Wq = (const float*)d_in[1];
    const float* Wk = (const float*)d_in[2];
    const float* Wv = (const float*)d_in[3];

    char* ws = (char*)d_ws;
    unsigned short* qb   = (unsigned short*)(ws);                    // 2 MB
    unsigned short* kb   = (unsigned short*)(ws + (2u << 20));       // 2 MB
    unsigned short* vt   = (unsigned short*)(ws + (4u << 20));       // 2 MB
    unsigned short* wt   = (unsigned short*)(ws + (6u << 20));       // 96 KB (pad 128K)
    unsigned short* pack = (unsigned short*)(ws + (6u << 20) + 131072);        // 7.34 MB
    float2*         mls  = (float2*)(ws + (6u << 20) + 131072 + 7340032);      // 1 MB
    float* out = (float*)d_out;

    hipLaunchKernelGGL(wconv_kernel, dim3(3), dim3(256), 0, stream, Wq, Wk, Wv, wt);
    hipLaunchKernelGGL(proj_kernel, dim3(M_ / 32), dim3(384), 0, stream, x, wt, qb, kb, vt);
    hipLaunchKernelGGL(attn_kernel, dim3(32, 128), dim3(256), 0, stream,
                       qb, kb, vt, out, pack, mls);
    hipLaunchKernelGGL(merge_kernel, dim3(256), dim3(256), 0, stream, out, pack, mls);
}